// Round 12
// baseline (462.980 us; speedup 1.0000x reference)
//
#include <hip/hip_runtime.h>
#include <hip/hip_bf16.h>
#include <cstdint>
#include <cstddef>

#define S_LEN 2048
#define HID_DIM 4096
#define NH 32
#define NKV 8
#define HD 128
#define LOG2E 1.4426950408889634f
#define SCALE 0.08838834764831845f

typedef __attribute__((ext_vector_type(8))) short bf16x8;
typedef __attribute__((ext_vector_type(4))) float f32x4;
typedef __attribute__((ext_vector_type(16))) float f32x16;
typedef __attribute__((ext_vector_type(4))) short short4v;
typedef __attribute__((ext_vector_type(4))) unsigned u32x4;

__device__ __forceinline__ short f2bf(float f) {
  union { float f; unsigned u; } v; v.f = f;
  return (short)((v.u + 0x7fffu + ((v.u >> 16) & 1u)) >> 16);
}
__device__ __forceinline__ float bf2f(short s) {
  union { unsigned u; float f; } v; v.u = ((unsigned)(unsigned short)s) << 16;
  return v.f;
}
__device__ __forceinline__ unsigned cvt_pk_bf16(float lo, float hi) {
  unsigned r;
  asm("v_cvt_pk_bf16_f32 %0, %1, %2" : "=v"(r) : "v"(lo), "v"(hi));
  return r;
}
__device__ __forceinline__ void gld_lds16(const void* g, void* l) {
  __builtin_amdgcn_global_load_lds((const __attribute__((address_space(1))) unsigned*)g,
                                   (__attribute__((address_space(3))) unsigned*)l, 16, 0, 0);
}

#define WAITVM4() asm volatile("s_waitcnt vmcnt(4)" ::: "memory")
#define WAITVM0() asm volatile("s_waitcnt vmcnt(0)" ::: "memory")

// ---------------- fp32 -> bf16 elementwise ----------------
__global__ void cvt_kernel(const float* __restrict__ in, short* __restrict__ out, int n) {
  int i = (blockIdx.x * 256 + threadIdx.x) * 4;
  if (i < n) {
    float4 f = *(const float4*)(in + i);
    short4v o = { f2bf(f.x), f2bf(f.y), f2bf(f.z), f2bf(f.w) };
    *(short4v*)(out + i) = o;
  }
}

// ---------------- fp32 [R][C] -> bf16 [C][R] transpose-convert ----------------
__global__ void tconv_kernel(const float* __restrict__ in, short* __restrict__ out, int R, int C) {
  __shared__ float tile[32][33];
  int tr = blockIdx.y * 32, tc = blockIdx.x * 32;
  int tx = threadIdx.x & 31, ty = threadIdx.x >> 5; // ty 0..7
#pragma unroll
  for (int i = 0; i < 32; i += 8)
    tile[ty + i][tx] = in[(size_t)(tr + ty + i) * C + tc + tx];
  __syncthreads();
#pragma unroll
  for (int i = 0; i < 32; i += 8)
    out[(size_t)(tc + ty + i) * R + tr + tx] = f2bf(tile[tx][ty + i]);
}

// ---------------- GEMM: C[M][N] = A[M][K] * Bt[N][K]^T ----------------
// Double-buffered LDS, counted vmcnt, 4 blocks/CU, per-XCD squarish regions.
// MODE 2: write fp32 out[m][n]
// MODE 3: fused QKV epilogue.
template<int MODE>
__global__ __launch_bounds__(256, 4) void gemm_bt_kernel(
    const short* __restrict__ A, const short* __restrict__ Bt,
    void* __restrict__ Cout, int M, int N, int K, int rchunk, int cchunk)
{
  __shared__ short As[2][128 * 32];
  __shared__ short Bs[2][128 * 32];
  const int tid = threadIdx.x;
  const int lane = tid & 63;
  const int w = tid >> 6;
  const int wm = w >> 1, wn = w & 1;
  const int xcd = blockIdx.x & 7;
  const int local = blockIdx.x >> 3;
  const int by = (xcd >> 2) * rchunk + (local % rchunk);
  const int bx = (xcd & 3) * cchunk + (local / rchunk);
  const int m0 = by * 128, n0 = bx * 128;

  auto stage = [&](int bb, int k0) {
#pragma unroll
    for (int rep = 0; rep < 2; rep++) {
      int c = rep * 256 + tid;
      int row = c >> 2, slot = c & 3;
      int gs = slot ^ (row & 3);
      gld_lds16(A + (size_t)(m0 + row) * K + k0 + gs * 8, &As[bb][c * 8]);
      gld_lds16(Bt + (size_t)(n0 + row) * K + k0 + gs * 8, &Bs[bb][c * 8]);
    }
  };

  f32x4 acc[4][4];
#pragma unroll
  for (int i = 0; i < 4; i++)
#pragma unroll
    for (int j = 0; j < 4; j++) acc[i][j] = (f32x4){0.f, 0.f, 0.f, 0.f};

  const int NT = K >> 5;
  stage(0, 0);
  for (int kt = 0; kt < NT; kt++) {
    const int b = kt & 1;
    if (kt + 1 < NT) { stage(b ^ 1, (kt + 1) << 5); WAITVM4(); }
    else             { WAITVM0(); }
    __builtin_amdgcn_s_barrier();

    bf16x8 af[4], bf[4];
#pragma unroll
    for (int ms = 0; ms < 4; ms++) {
      int row = wm * 64 + ms * 16 + (lane & 15);
      af[ms] = *(const bf16x8*)(&As[b][row * 32 + (((lane >> 4) ^ (row & 3)) << 3)]);
    }
#pragma unroll
    for (int ns = 0; ns < 4; ns++) {
      int row = wn * 64 + ns * 16 + (lane & 15);
      bf[ns] = *(const bf16x8*)(&Bs[b][row * 32 + (((lane >> 4) ^ (row & 3)) << 3)]);
    }
#pragma unroll
    for (int ms = 0; ms < 4; ms++)
#pragma unroll
      for (int ns = 0; ns < 4; ns++)
        acc[ms][ns] = __builtin_amdgcn_mfma_f32_16x16x32_bf16(af[ms], bf[ns], acc[ms][ns], 0, 0, 0);

    __builtin_amdgcn_s_barrier();
  }

#pragma unroll
  for (int ms = 0; ms < 4; ms++) {
    int mb = m0 + wm * 64 + ms * 16 + ((lane >> 4) << 2);
#pragma unroll
    for (int ns = 0; ns < 4; ns++) {
      int n = n0 + wn * 64 + ns * 16 + (lane & 15);
      if (MODE == 3) {
        short* o = (short*)Cout;
        if (n < NH * HD) {
          int head = n >> 7, d = n & 127;
#pragma unroll
          for (int r = 0; r < 4; r++)
            o[((size_t)head * M + (mb + r)) * HD + d] = f2bf(acc[ms][ns][r]);
        } else if (n < (NH + NKV) * HD) {
          int head = (n - NH * HD) >> 7, d = n & 127;
          short* ok = o + (size_t)NH * S_LEN * HD;
#pragma unroll
          for (int r = 0; r < 4; r++)
            ok[((size_t)head * M + (mb + r)) * HD + d] = f2bf(acc[ms][ns][r]);
        } else {
          int head = (n - (NH + NKV) * HD) >> 7, d = n & 127;
          short* ov = o + (size_t)(NH + NKV) * S_LEN * HD;
          short4v pk;
#pragma unroll
          for (int r = 0; r < 4; r++) pk[r] = f2bf(acc[ms][ns][r]);
          *(short4v*)(ov + ((size_t)head * HD + d) * M + mb) = pk;
        }
      } else {
        float* o = (float*)Cout;
#pragma unroll
        for (int r = 0; r < 4; r++)
          o[(size_t)(mb + r) * N + n] = acc[ms][ns][r];
      }
    }
  }
}

// ---------------- RoPE in-place on Q [NH][S][HD] and K [NKV][S][HD] (bf16) ----------------
__global__ void rope_kernel(short* __restrict__ q, short* __restrict__ k,
                            const int* __restrict__ pos_ids) {
  const int s = blockIdx.x;
  const int hh = blockIdx.y * 4 + threadIdx.y;  // 0..39
  const int d = threadIdx.x;                    // 0..63
  const float pos = (float)pos_ids[s];
  const float inv = __expf(-(float)d * 0.14391157f); // ln(10000)/64
  float sn, c;
  __sincosf(pos * inv, &sn, &c);
  short* base = (hh < NH) ? (q + ((size_t)hh * S_LEN + s) * HD)
                          : (k + ((size_t)(hh - NH) * S_LEN + s) * HD);
  float x1 = bf2f(base[d]), x2 = bf2f(base[d + 64]);
  base[d] = f2bf(x1 * c - x2 * sn);
  base[d + 64] = f2bf(x2 * c + x1 * sn);
}

// ---------------- flash attention + eviction scores (32x32x16 MFMA) ----------------
// 512 blocks x 256 threads. Block = (head, 128-row strip qt, heavy-first).
// 4 waves, each OWNS 32 q-rows FULLY (both key halves: 32 MFMA per staged
// tile per wave -> 2x staging amortization vs kh-split; no O/l combine LDS).
// kvh == XCD. K double-buffered (32KB) with key bits 2<->3 swapped (swapped
// QK^T C[key][q] output is lane-local for the PV A-frags); V single-buffered
// (16KB; staged after barrier A, drained by vmcnt(4) before barrier B while
// next K stays in flight). 48.5KB LDS -> 3 blocks/CU (12 waves).
// Fixed softmax basis m==0; l deferred (one shfl reduce per wave).
// Phase 2 (colsums): barrier-free, K fragments direct from L2, per-wave.
__global__ __launch_bounds__(256, 3) void attn_kernel(
    const short* __restrict__ Qr, const short* __restrict__ Kr, const short* __restrict__ Vt,
    short* __restrict__ attn_out, float* __restrict__ scores)
{
  __shared__ short Ks[2][64 * 128];  // 32KB dbuf, 16B slots XOR-swizzled by (row&7)
  __shared__ short Vs[128 * 64];     // 16KB single buffer, swizzled by (d&7)

  const int tid = threadIdx.x;
  const int lane = tid & 63;
  const int w = tid >> 6;        // 0..3 row group
  const int h2 = lane >> 5;
  const int l31 = lane & 31;
  const int xcd = blockIdx.x & 7;
  const int j = blockIdx.x >> 3; // 0..63
  const int h = xcd * 4 + (j & 3);
  const int qt = 15 - (j >> 2);  // heavy strips first
  const int kvh = xcd;
  const float CS = SCALE * LOG2E;

  const short* KrB = Kr + (size_t)kvh * S_LEN * HD;
  const short* VtB = Vt + (size_t)kvh * HD * S_LEN;

  const int nt = 2 * qt + 2;
  const int qbase = qt * 128 + w * 32;
  const int qglob = qbase + l31;
  const int qmaxw = qbase + 31;

  auto stageK = [&](int bb, int t) {
    const int kb2 = t * 64;
#pragma unroll
    for (int rep = 0; rep < 4; rep++) {
      int c = rep * 256 + tid;
      int x = c >> 4, slot = c & 15;
      int key = (x & 0x33) | ((x & 4) << 1) | ((x & 8) >> 1);  // swap bits 2,3
      int gs = slot ^ (x & 7);
      gld_lds16(KrB + (size_t)(kb2 + key) * HD + gs * 8, &Ks[bb][c * 8]);
    }
  };
  auto stageV = [&](int t) {
    const int kb2 = t * 64;
#pragma unroll
    for (int rep = 0; rep < 4; rep++) {
      int c = rep * 256 + tid;
      int d = c >> 3, slot = c & 7;
      int gs = slot ^ (d & 7);
      gld_lds16(VtB + (size_t)d * S_LEN + kb2 + gs * 8, &Vs[c * 8]);
    }
  };

  // Q fragments: q = qglob, hd = kc*16 + h2*8 + e
  bf16x8 qf[8];
  {
    const short* qrow = Qr + ((size_t)h * S_LEN + qglob) * HD + h2 * 8;
#pragma unroll
    for (int kc = 0; kc < 8; kc++) qf[kc] = *(const bf16x8*)(qrow + kc * 16);
  }

  f32x16 oacc[4];
#pragma unroll
  for (int i = 0; i < 4; i++) oacc[i] = (f32x16)(0.f);
  float lsum = 0.f;

  // ---------- phase 1 ----------
  stageK(0, 0);
  for (int t = 0; t < nt; t++) {
    const int b = t & 1;
    const int kb = t * 64;
    WAITVM0();                       // K(t) landed
    __builtin_amdgcn_s_barrier();    // barrier A: Ks[b] ready, Vs free

    stageV(t);
    if (t + 1 < nt) stageK(b ^ 1, t + 1);

    bf16x8 pa[4];
    const bool live = (kb <= qmaxw);
    if (live) {
      // QK^T swapped: C[permkey][q], both key halves
      f32x16 sf[2];
      sf[0] = (f32x16)(0.f); sf[1] = (f32x16)(0.f);
      __builtin_amdgcn_s_setprio(1);
#pragma unroll
      for (int kc = 0; kc < 8; kc++)
#pragma unroll
        for (int bl = 0; bl < 2; bl++) {
          int x = bl * 32 + l31;
          bf16x8 kf = *(const bf16x8*)(&Ks[b][x * 128 + (((kc * 2 + h2) ^ (x & 7)) << 3)]);
          sf[bl] = __builtin_amdgcn_mfma_f32_32x32x16_bf16(kf, qf[kc], sf[bl], 0, 0, 0);
        }
      __builtin_amdgcn_s_setprio(0);

      // softmax (fixed basis 0); key of sf[bl][4a+cc] =
      // kb + bl*32 + (a>>1)*16 + h2*8 + (a&1)*4 + cc
      float p[2][16];
      const bool diag = (kb + 63 > qbase);
#pragma unroll
      for (int bl = 0; bl < 2; bl++)
#pragma unroll
        for (int a = 0; a < 4; a++)
#pragma unroll
          for (int cc = 0; cc < 4; cc++) {
            float pv = exp2f(sf[bl][a * 4 + cc] * CS);
            if (diag) {
              int key = kb + bl * 32 + (a >> 1) * 16 + h2 * 8 + (a & 1) * 4 + cc;
              if (key > qglob) pv = 0.f;
            }
            p[bl][a * 4 + cc] = pv;
            lsum += pv;
          }

      // pack PV A-frags: pa[s] elem e = p[s>>1][8*(s&1) + e]
#pragma unroll
      for (int s = 0; s < 4; s++) {
        const int bl = s >> 1, base = 8 * (s & 1);
        u32x4 pw;
        pw[0] = cvt_pk_bf16(p[bl][base + 0], p[bl][base + 1]);
        pw[1] = cvt_pk_bf16(p[bl][base + 2], p[bl][base + 3]);
        pw[2] = cvt_pk_bf16(p[bl][base + 4], p[bl][base + 5]);
        pw[3] = cvt_pk_bf16(p[bl][base + 6], p[bl][base + 7]);
        pa[s] = __builtin_bit_cast(bf16x8, pw);
      }
    }

    if (t + 1 < nt) WAITVM4();       // drain V(t), keep K(t+1) in flight
    else           WAITVM0();
    __builtin_amdgcn_s_barrier();    // barrier B: Vs valid

    if (live) {
      // PV: C[q][d], all 4 key slices
      __builtin_amdgcn_s_setprio(1);
#pragma unroll
      for (int s = 0; s < 4; s++)
#pragma unroll
        for (int db = 0; db < 4; db++) {
          int d = db * 32 + l31;
          bf16x8 vf = *(const bf16x8*)(&Vs[d * 64 + (((s * 2 + h2) ^ (d & 7)) << 3)]);
          oacc[db] = __builtin_amdgcn_mfma_f32_32x32x16_bf16(pa[s], vf, oacc[db], 0, 0, 0);
        }
      __builtin_amdgcn_s_setprio(0);
    }
  }

  // l reduce (h2 halves hold different keys of same q)
  lsum += __shfl_xor(lsum, 32);
  float rlv = 1.f / lsum;            // valid for q-row = l31
  float rl16[16];
#pragma unroll
  for (int r16 = 0; r16 < 16; r16++)
    rl16[r16] = __shfl(rlv, (r16 & 3) + 8 * (r16 >> 2) + 4 * h2);

  // write O: lane holds d-col = db*32 + l31, q-rows by reg
#pragma unroll
  for (int db = 0; db < 4; db++) {
    int d = db * 32 + l31;
#pragma unroll
    for (int r16 = 0; r16 < 16; r16++) {
      int qq = qbase + (r16 & 3) + 8 * (r16 >> 2) + 4 * h2;
      attn_out[(size_t)qq * HID_DIM + h * HD + d] = f2bf(oacc[db][r16] * rl16[r16]);
    }
  }

  // ---------- phase 2: colsums, direct from L2, barrier-free, per wave ----------
  float* sc = scores + (size_t)kvh * S_LEN;
  const int ntw = qmaxw / 64 + 1;
  for (int t = 0; t < ntw; t++) {
    const int kb = t * 64;
    f32x16 sg[2];
    sg[0] = (f32x16)(0.f); sg[1] = (f32x16)(0.f);
    __builtin_amdgcn_s_setprio(1);
#pragma unroll
    for (int kc = 0; kc < 8; kc++)
#pragma unroll
      for (int bl = 0; bl < 2; bl++) {
        bf16x8 kf = *(const bf16x8*)(KrB + (size_t)(kb + bl * 32 + l31) * HD + kc * 16 + h2 * 8);
        sg[bl] = __builtin_amdgcn_mfma_f32_32x32x16_bf16(qf[kc], kf, sg[bl], 0, 0, 0);
      }
    __builtin_amdgcn_s_setprio(0);

    const bool diag = (kb + 63 > qbase);
#pragma unroll
    for (int bl = 0; bl < 2; bl++) {
      int key = kb + bl * 32 + l31;
      float sum = 0.f;
#pragma unroll
      for (int r16 = 0; r16 < 16; r16++) {
        float pv = exp2f(sg[bl][r16] * CS) * rl16[r16];
        if (diag && key > qbase + (r16 & 3) + 8 * (r16 >> 2) + 4 * h2) pv = 0.f;
        sum += pv;
      }
      sum += __shfl_xor(sum, 32);
      if (lane < 32) atomicAdd(&sc[key], sum);
    }
  }
}

// ---------------- launch ----------------
extern "C" void kernel_launch(void* const* d_in, const int* in_sizes, int n_in,
                              void* d_out, int out_size, void* d_ws, size_t ws_size,
                              hipStream_t stream) {
  const float* hs = (const float*)d_in[0];
  const float* wq = (const float*)d_in[1];
  const float* wk = (const float*)d_in[2];
  const float* wv = (const float*)d_in[3];
  const float* wo = (const float*)d_in[4];
  const int* pos = (const int*)d_in[5];
  float* out = (float*)d_out;

  char* ws = (char*)d_ws;
  const size_t off_hs   = 0;
  const size_t off_wqT  = off_hs   + (size_t)S_LEN * HID_DIM * 2;
  const size_t off_wkT  = off_wqT  + (size_t)HID_DIM * HID_DIM * 2;
  const size_t off_wvT  = off_wkT  + (size_t)1024 * HID_DIM * 2;
  const size_t off_woT  = off_wvT  + (size_t)1024 * HID_DIM * 2;
  const size_t off_Qr   = off_woT  + (size_t)HID_DIM * HID_DIM * 2;
  const size_t off_Kr   = off_Qr   + (size_t)NH * S_LEN * HD * 2;
  const size_t off_Vt   = off_Kr   + (size_t)NKV * S_LEN * HD * 2;
  const size_t off_attn = off_Vt   + (size_t)NKV * HD * S_LEN * 2;

  short* hsb  = (short*)(ws + off_hs);
  short* wqT  = (short*)(ws + off_wqT);
  short* wkT  = (short*)(ws + off_wkT);
  short* wvT  = (short*)(ws + off_wvT);
  short* woT  = (short*)(ws + off_woT);
  short* Qr   = (short*)(ws + off_Qr);
  short* Kr   = (short*)(ws + off_Kr);
  short* Vt   = (short*)(ws + off_Vt);
  short* attb = (short*)(ws + off_attn);

  cvt_kernel<<<dim3((S_LEN * HID_DIM) / 1024), 256, 0, stream>>>(hs, hsb, S_LEN * HID_DIM);
  tconv_kernel<<<dim3(128, 128), 256, 0, stream>>>(wq, wqT, HID_DIM, HID_DIM);
  tconv_kernel<<<dim3(32, 128), 256, 0, stream>>>(wk, wkT, HID_DIM, 1024);
  tconv_kernel<<<dim3(32, 128), 256, 0, stream>>>(wv, wvT, HID_DIM, 1024);
  tconv_kernel<<<dim3(128, 128), 256, 0, stream>>>(wo, woT, HID_DIM, HID_DIM);

  gemm_bt_kernel<3><<<768, 256, 0, stream>>>(hsb, wqT, Qr, S_LEN, 6144, HID_DIM, 8, 12);

  rope_kernel<<<dim3(S_LEN, 10), dim3(64, 4), 0, stream>>>(Qr, Kr, pos);

  hipMemsetAsync(out + (size_t)S_LEN * HID_DIM, 0, (size_t)NKV * S_LEN * sizeof(float), stream);
  attn_kernel<<<512, 256, 0, stream>>>(Qr, Kr, Vt, attb, out + (size_t)S_LEN * HID_DIM);

  gemm_bt_kernel<2><<<512, 256, 0, stream>>>(attb, woT, out, S_LEN, HID_DIM, HID_DIM, 8, 8);
}

// Round 13
// 399.271 us; speedup vs baseline: 1.1596x; 1.1596x over previous
//
#include <hip/hip_runtime.h>
#include <hip/hip_bf16.h>
#include <cstdint>
#include <cstddef>

#define S_LEN 2048
#define HID_DIM 4096
#define NH 32
#define NKV 8
#define HD 128
#define LOG2E 1.4426950408889634f
#define SCALE 0.08838834764831845f

typedef __attribute__((ext_vector_type(8))) short bf16x8;
typedef __attribute__((ext_vector_type(4))) float f32x4;
typedef __attribute__((ext_vector_type(16))) float f32x16;
typedef __attribute__((ext_vector_type(4))) short short4v;
typedef __attribute__((ext_vector_type(4))) unsigned u32x4;

__device__ __forceinline__ short f2bf(float f) {
  union { float f; unsigned u; } v; v.f = f;
  return (short)((v.u + 0x7fffu + ((v.u >> 16) & 1u)) >> 16);
}
__device__ __forceinline__ float bf2f(short s) {
  union { unsigned u; float f; } v; v.u = ((unsigned)(unsigned short)s) << 16;
  return v.f;
}
__device__ __forceinline__ unsigned cvt_pk_bf16(float lo, float hi) {
  unsigned r;
  asm("v_cvt_pk_bf16_f32 %0, %1, %2" : "=v"(r) : "v"(lo), "v"(hi));
  return r;
}
__device__ __forceinline__ void gld_lds16(const void* g, void* l) {
  __builtin_amdgcn_global_load_lds((const __attribute__((address_space(1))) unsigned*)g,
                                   (__attribute__((address_space(3))) unsigned*)l, 16, 0, 0);
}

#define WAITVM4() asm volatile("s_waitcnt vmcnt(4)" ::: "memory")
#define WAITVM0() asm volatile("s_waitcnt vmcnt(0)" ::: "memory")

// ---------------- fp32 -> bf16 elementwise ----------------
__global__ void cvt_kernel(const float* __restrict__ in, short* __restrict__ out, int n) {
  int i = (blockIdx.x * 256 + threadIdx.x) * 4;
  if (i < n) {
    float4 f = *(const float4*)(in + i);
    short4v o = { f2bf(f.x), f2bf(f.y), f2bf(f.z), f2bf(f.w) };
    *(short4v*)(out + i) = o;
  }
}

// ---------------- fp32 [R][C] -> bf16 [C][R] transpose-convert ----------------
__global__ void tconv_kernel(const float* __restrict__ in, short* __restrict__ out, int R, int C) {
  __shared__ float tile[32][33];
  int tr = blockIdx.y * 32, tc = blockIdx.x * 32;
  int tx = threadIdx.x & 31, ty = threadIdx.x >> 5; // ty 0..7
#pragma unroll
  for (int i = 0; i < 32; i += 8)
    tile[ty + i][tx] = in[(size_t)(tr + ty + i) * C + tc + tx];
  __syncthreads();
#pragma unroll
  for (int i = 0; i < 32; i += 8)
    out[(size_t)(tc + ty + i) * R + tr + tx] = f2bf(tile[tx][ty + i]);
}

// ---------------- GEMM: C[M][N] = A[M][K] * Bt[N][K]^T ----------------
// Double-buffered LDS, counted vmcnt, 4 blocks/CU, per-XCD squarish regions.
// MODE 3: fused QKV epilogue.
template<int MODE>
__global__ __launch_bounds__(256, 4) void gemm_bt_kernel(
    const short* __restrict__ A, const short* __restrict__ Bt,
    void* __restrict__ Cout, int M, int N, int K, int rchunk, int cchunk)
{
  __shared__ short As[2][128 * 32];
  __shared__ short Bs[2][128 * 32];
  const int tid = threadIdx.x;
  const int lane = tid & 63;
  const int w = tid >> 6;
  const int wm = w >> 1, wn = w & 1;
  const int xcd = blockIdx.x & 7;
  const int local = blockIdx.x >> 3;
  const int by = (xcd >> 2) * rchunk + (local % rchunk);
  const int bx = (xcd & 3) * cchunk + (local / rchunk);
  const int m0 = by * 128, n0 = bx * 128;

  auto stage = [&](int bb, int k0) {
#pragma unroll
    for (int rep = 0; rep < 2; rep++) {
      int c = rep * 256 + tid;
      int row = c >> 2, slot = c & 3;
      int gs = slot ^ (row & 3);
      gld_lds16(A + (size_t)(m0 + row) * K + k0 + gs * 8, &As[bb][c * 8]);
      gld_lds16(Bt + (size_t)(n0 + row) * K + k0 + gs * 8, &Bs[bb][c * 8]);
    }
  };

  f32x4 acc[4][4];
#pragma unroll
  for (int i = 0; i < 4; i++)
#pragma unroll
    for (int j = 0; j < 4; j++) acc[i][j] = (f32x4){0.f, 0.f, 0.f, 0.f};

  const int NT = K >> 5;
  stage(0, 0);
  for (int kt = 0; kt < NT; kt++) {
    const int b = kt & 1;
    if (kt + 1 < NT) { stage(b ^ 1, (kt + 1) << 5); WAITVM4(); }
    else             { WAITVM0(); }
    __builtin_amdgcn_s_barrier();

    bf16x8 af[4], bf[4];
#pragma unroll
    for (int ms = 0; ms < 4; ms++) {
      int row = wm * 64 + ms * 16 + (lane & 15);
      af[ms] = *(const bf16x8*)(&As[b][row * 32 + (((lane >> 4) ^ (row & 3)) << 3)]);
    }
#pragma unroll
    for (int ns = 0; ns < 4; ns++) {
      int row = wn * 64 + ns * 16 + (lane & 15);
      bf[ns] = *(const bf16x8*)(&Bs[b][row * 32 + (((lane >> 4) ^ (row & 3)) << 3)]);
    }
#pragma unroll
    for (int ms = 0; ms < 4; ms++)
#pragma unroll
      for (int ns = 0; ns < 4; ns++)
        acc[ms][ns] = __builtin_amdgcn_mfma_f32_16x16x32_bf16(af[ms], bf[ns], acc[ms][ns], 0, 0, 0);

    __builtin_amdgcn_s_barrier();
  }

#pragma unroll
  for (int ms = 0; ms < 4; ms++) {
    int mb = m0 + wm * 64 + ms * 16 + ((lane >> 4) << 2);
#pragma unroll
    for (int ns = 0; ns < 4; ns++) {
      int n = n0 + wn * 64 + ns * 16 + (lane & 15);
      if (MODE == 3) {
        short* o = (short*)Cout;
        if (n < NH * HD) {
          int head = n >> 7, d = n & 127;
#pragma unroll
          for (int r = 0; r < 4; r++)
            o[((size_t)head * M + (mb + r)) * HD + d] = f2bf(acc[ms][ns][r]);
        } else if (n < (NH + NKV) * HD) {
          int head = (n - NH * HD) >> 7, d = n & 127;
          short* ok = o + (size_t)NH * S_LEN * HD;
#pragma unroll
          for (int r = 0; r < 4; r++)
            ok[((size_t)head * M + (mb + r)) * HD + d] = f2bf(acc[ms][ns][r]);
        } else {
          int head = (n - (NH + NKV) * HD) >> 7, d = n & 127;
          short* ov = o + (size_t)(NH + NKV) * S_LEN * HD;
          short4v pk;
#pragma unroll
          for (int r = 0; r < 4; r++) pk[r] = f2bf(acc[ms][ns][r]);
          *(short4v*)(ov + ((size_t)head * HD + d) * M + mb) = pk;
        }
      } else {
        float* o = (float*)Cout;
#pragma unroll
        for (int r = 0; r < 4; r++)
          o[(size_t)(mb + r) * N + n] = acc[ms][ns][r];
      }
    }
  }
}

// ---------------- RoPE in-place on Q [NH][S][HD] and K [NKV][S][HD] (bf16) ----------------
__global__ void rope_kernel(short* __restrict__ q, short* __restrict__ k,
                            const int* __restrict__ pos_ids) {
  const int s = blockIdx.x;
  const int hh = blockIdx.y * 4 + threadIdx.y;  // 0..39
  const int d = threadIdx.x;                    // 0..63
  const float pos = (float)pos_ids[s];
  const float inv = __expf(-(float)d * 0.14391157f); // ln(10000)/64
  float sn, c;
  __sincosf(pos * inv, &sn, &c);
  short* base = (hh < NH) ? (q + ((size_t)hh * S_LEN + s) * HD)
                          : (k + ((size_t)(hh - NH) * S_LEN + s) * HD);
  float x1 = bf2f(base[d]), x2 = bf2f(base[d + 64]);
  base[d] = f2bf(x1 * c - x2 * sn);
  base[d + 64] = f2bf(x2 * c + x1 * sn);
}

// ---------------- flash attention, PHASE 1 ONLY (32x32x16 MFMA) ----------------
// r11 structure verbatim minus colsum phase: 1024 blocks x 256 threads
// (4 waves = 2 rowgroups x 2 key-halves), one 64-row strip per block
// (heavy-first), kvh == XCD, 3 blocks/CU. K dbuf (32KB, key bits 2<->3
// swapped -> swapped QK^T output lane-local for PV A-frag); V single-buffer
// (16KB, staged after barrier A, drained by vmcnt(4) before barrier B).
// Fixed softmax basis m==0; l deferred; O/l combined across key-halves via
// LDS. Writes rl = 1/l per (head,q) to rlw for the offloaded colsum pass.
__global__ __launch_bounds__(256, 3) void attn_kernel(
    const short* __restrict__ Qr, const short* __restrict__ Kr, const short* __restrict__ Vt,
    short* __restrict__ attn_out, float* __restrict__ rlw)
{
  __shared__ short Ks[2][64 * 128];
  __shared__ short Vs[128 * 64];
  __shared__ float lbuf[64];

  const int tid = threadIdx.x;
  const int lane = tid & 63;
  const int w = tid >> 6;        // 0..3
  const int r = w & 1;           // row group
  const int kh = w >> 1;         // key half
  const int h2 = lane >> 5;
  const int l31 = lane & 31;
  const int xcd = blockIdx.x & 7;
  const int j = blockIdx.x >> 3; // 0..127
  const int h = xcd * 4 + (j & 3);
  const int qt = 31 - (j >> 2);  // heavy strips first
  const int kvh = xcd;
  const float CS = SCALE * LOG2E;

  const short* KrB = Kr + (size_t)kvh * S_LEN * HD;
  const short* VtB = Vt + (size_t)kvh * HD * S_LEN;

  const int nt = qt + 1;
  const int qbase = qt * 64 + r * 32;
  const int qglob = qbase + l31;

  float* obuf = (float*)Ks;      // valid after phase 1

  auto stageK = [&](int bb, int t) {
    const int kb2 = t * 64;
#pragma unroll
    for (int rep = 0; rep < 4; rep++) {
      int c = rep * 256 + tid;
      int x = c >> 4, slot = c & 15;
      int key = (x & 0x33) | ((x & 4) << 1) | ((x & 8) >> 1);  // swap bits 2,3
      int gs = slot ^ (x & 7);
      gld_lds16(KrB + (size_t)(kb2 + key) * HD + gs * 8, &Ks[bb][c * 8]);
    }
  };
  auto stageV = [&](int t) {
    const int kb2 = t * 64;
#pragma unroll
    for (int rep = 0; rep < 4; rep++) {
      int c = rep * 256 + tid;
      int d = c >> 3, slot = c & 7;
      int gs = slot ^ (d & 7);
      gld_lds16(VtB + (size_t)d * S_LEN + kb2 + gs * 8, &Vs[c * 8]);
    }
  };

  // Q fragments: q = qglob, hd = kc*16 + h2*8 + e
  bf16x8 qf[8];
  {
    const short* qrow = Qr + ((size_t)h * S_LEN + qglob) * HD + h2 * 8;
#pragma unroll
    for (int kc = 0; kc < 8; kc++) qf[kc] = *(const bf16x8*)(qrow + kc * 16);
  }

  f32x16 oacc[4];
#pragma unroll
  for (int i = 0; i < 4; i++) oacc[i] = (f32x16)(0.f);
  float lsum = 0.f;

  // ---------- phase 1 ----------
  stageK(0, 0);
  for (int t = 0; t < nt; t++) {
    const int b = t & 1;
    const int kb = t * 64;
    WAITVM0();                       // K(t) landed
    __builtin_amdgcn_s_barrier();    // barrier A: Ks[b] ready, Vs free

    stageV(t);
    if (t + 1 < nt) stageK(b ^ 1, t + 1);

    // QK^T swapped: C[permkey][q], this wave's key half kh
    f32x16 sf = (f32x16)(0.f);
    const int x = kh * 32 + l31;
    __builtin_amdgcn_s_setprio(1);
#pragma unroll
    for (int kc = 0; kc < 8; kc++) {
      bf16x8 kf = *(const bf16x8*)(&Ks[b][x * 128 + (((kc * 2 + h2) ^ (x & 7)) << 3)]);
      sf = __builtin_amdgcn_mfma_f32_32x32x16_bf16(kf, qf[kc], sf, 0, 0, 0);
    }
    __builtin_amdgcn_s_setprio(0);

    // softmax (fixed basis 0); key of sf[4a+cc] = kb + kh*32 + (a>>1)*16 + h2*8 + (a&1)*4 + cc
    float pv16[16];
    const bool diag = (kb + 63 > qbase);
#pragma unroll
    for (int a = 0; a < 4; a++)
#pragma unroll
      for (int cc = 0; cc < 4; cc++) {
        float pv = exp2f(sf[a * 4 + cc] * CS);
        if (diag) {
          int key = kb + kh * 32 + (a >> 1) * 16 + h2 * 8 + (a & 1) * 4 + cc;
          if (key > qglob) pv = 0.f;
        }
        pv16[a * 4 + cc] = pv;
        lsum += pv;
      }

    bf16x8 pa[2];
#pragma unroll
    for (int s = 0; s < 2; s++) {
      u32x4 pw;
      pw[0] = cvt_pk_bf16(pv16[8 * s + 0], pv16[8 * s + 1]);
      pw[1] = cvt_pk_bf16(pv16[8 * s + 2], pv16[8 * s + 3]);
      pw[2] = cvt_pk_bf16(pv16[8 * s + 4], pv16[8 * s + 5]);
      pw[3] = cvt_pk_bf16(pv16[8 * s + 6], pv16[8 * s + 7]);
      pa[s] = __builtin_bit_cast(bf16x8, pw);
    }

    if (t + 1 < nt) WAITVM4();       // drain V(t), keep K(t+1) in flight
    else           WAITVM0();
    __builtin_amdgcn_s_barrier();    // barrier B: Vs valid

    // PV: C[q][d], partial over this key half
    __builtin_amdgcn_s_setprio(1);
#pragma unroll
    for (int s = 0; s < 2; s++) {
      const int g = kh * 2 + s;      // 16-wide key slice
#pragma unroll
      for (int db = 0; db < 4; db++) {
        int d = db * 32 + l31;
        bf16x8 vf = *(const bf16x8*)(&Vs[d * 64 + (((g * 2 + h2) ^ (d & 7)) << 3)]);
        oacc[db] = __builtin_amdgcn_mfma_f32_32x32x16_bf16(pa[s], vf, oacc[db], 0, 0, 0);
      }
    }
    __builtin_amdgcn_s_setprio(0);
  }

  __builtin_amdgcn_s_barrier();      // all PV reads done; Ks reusable as obuf

  // ---------- O / l combine across key-halves ----------
  lsum += __shfl_xor(lsum, 32);      // combine h2 halves
  if (kh == 0) {
#pragma unroll
    for (int db = 0; db < 4; db++)
#pragma unroll
      for (int r16 = 0; r16 < 16; r16++) {
        int crow = (r16 & 3) + 8 * (r16 >> 2) + 4 * h2;
        obuf[(r * 32 + crow) * 128 + db * 32 + l31] = oacc[db][r16];
      }
    if (lane < 32) lbuf[r * 32 + l31] = lsum;
  }
  __builtin_amdgcn_s_barrier();

  if (kh == 1) {
    float ltot = lsum + lbuf[r * 32 + l31];
    float rlv = 1.f / ltot;
    float rl16[16];
#pragma unroll
    for (int r16 = 0; r16 < 16; r16++)
      rl16[r16] = __shfl(rlv, (r16 & 3) + 8 * (r16 >> 2) + 4 * h2);
#pragma unroll
    for (int db = 0; db < 4; db++) {
      int d = db * 32 + l31;
#pragma unroll
      for (int r16 = 0; r16 < 16; r16++) {
        int crow = (r16 & 3) + 8 * (r16 >> 2) + 4 * h2;
        float o = oacc[db][r16] + obuf[(r * 32 + crow) * 128 + d];
        attn_out[(size_t)(qbase + crow) * HID_DIM + h * HD + d] = f2bf(o * rl16[r16]);
      }
    }
    if (lane < 32) rlw[(size_t)h * S_LEN + qbase + l31] = rlv;  // for colsum pass
  }
}

// ---------------- fused O-proj GEMM + eviction colsums ----------------
// Blocks 0..511: MODE-2 GEMM (attb[2048x4096] x woT^T -> out fp32), identical
// to the proven dbuf/counted-vmcnt 128^2 structure (rchunk=cchunk=8).
// Blocks 512..1023: barrier-free colsum (r11's verified phase-2 math): per
// block (head, 128-row strip heavy-first), 4 waves x 32 q-rows, K fragments
// direct from L2, rl from rlw, atomicAdd into scores. Heterogeneous blocks
// co-resident on a CU hide each other's stalls (only overlap available on
// one stream).
__global__ __launch_bounds__(256, 4) void oproj_fused_kernel(
    const short* __restrict__ A, const short* __restrict__ Bt, float* __restrict__ Cout,
    const short* __restrict__ Qr, const short* __restrict__ Kr,
    const float* __restrict__ rlw, float* __restrict__ scores)
{
  __shared__ short As[2][128 * 32];
  __shared__ short Bs[2][128 * 32];
  const int tid = threadIdx.x;
  const int lane = tid & 63;
  const float CS = SCALE * LOG2E;

  if (blockIdx.x < 512) {
    const int w = tid >> 6;
    const int wm = w >> 1, wn = w & 1;
    const int xcd = blockIdx.x & 7;
    const int local = blockIdx.x >> 3;
    const int by = (xcd >> 2) * 8 + (local % 8);
    const int bx = (xcd & 3) * 8 + (local / 8);
    const int m0 = by * 128, n0 = bx * 128;
    const int M = S_LEN, N = HID_DIM, K = HID_DIM;

    auto stage = [&](int bb, int k0) {
#pragma unroll
      for (int rep = 0; rep < 2; rep++) {
        int c = rep * 256 + tid;
        int row = c >> 2, slot = c & 3;
        int gs = slot ^ (row & 3);
        gld_lds16(A + (size_t)(m0 + row) * K + k0 + gs * 8, &As[bb][c * 8]);
        gld_lds16(Bt + (size_t)(n0 + row) * K + k0 + gs * 8, &Bs[bb][c * 8]);
      }
    };

    f32x4 acc[4][4];
#pragma unroll
    for (int i = 0; i < 4; i++)
#pragma unroll
      for (int jj = 0; jj < 4; jj++) acc[i][jj] = (f32x4){0.f, 0.f, 0.f, 0.f};

    const int NT = K >> 5;
    stage(0, 0);
    for (int kt = 0; kt < NT; kt++) {
      const int b = kt & 1;
      if (kt + 1 < NT) { stage(b ^ 1, (kt + 1) << 5); WAITVM4(); }
      else             { WAITVM0(); }
      __builtin_amdgcn_s_barrier();

      bf16x8 af[4], bf[4];
#pragma unroll
      for (int ms = 0; ms < 4; ms++) {
        int row = wm * 64 + ms * 16 + (lane & 15);
        af[ms] = *(const bf16x8*)(&As[b][row * 32 + (((lane >> 4) ^ (row & 3)) << 3)]);
      }
#pragma unroll
      for (int ns = 0; ns < 4; ns++) {
        int row = wn * 64 + ns * 16 + (lane & 15);
        bf[ns] = *(const bf16x8*)(&Bs[b][row * 32 + (((lane >> 4) ^ (row & 3)) << 3)]);
      }
#pragma unroll
      for (int ms = 0; ms < 4; ms++)
#pragma unroll
        for (int ns = 0; ns < 4; ns++)
          acc[ms][ns] = __builtin_amdgcn_mfma_f32_16x16x32_bf16(af[ms], bf[ns], acc[ms][ns], 0, 0, 0);

      __builtin_amdgcn_s_barrier();
    }

#pragma unroll
    for (int ms = 0; ms < 4; ms++) {
      int mb = m0 + wm * 64 + ms * 16 + ((lane >> 4) << 2);
#pragma unroll
      for (int ns = 0; ns < 4; ns++) {
        int n = n0 + wn * 64 + ns * 16 + (lane & 15);
#pragma unroll
        for (int r = 0; r < 4; r++)
          Cout[(size_t)(mb + r) * N + n] = acc[ms][ns][r];
      }
    }
  } else {
    // ---------------- colsum path (no LDS, no barriers) ----------------
    const int cb = blockIdx.x - 512;
    const int xcd = cb & 7;
    const int j = cb >> 3;             // 0..63
    const int h = xcd * 4 + (j & 3);
    const int qt = 15 - (j >> 2);      // 128-row strips, heavy-first
    const int kvh = xcd;
    const int w = tid >> 6;            // 0..3
    const int h2 = lane >> 5;
    const int l31 = lane & 31;
    const int qbase = qt * 128 + w * 32;

    const short* KrB = Kr + (size_t)kvh * S_LEN * HD;

    bf16x8 qf[8];
    {
      const short* qrow = Qr + ((size_t)h * S_LEN + qbase + l31) * HD + h2 * 8;
#pragma unroll
      for (int kc = 0; kc < 8; kc++) qf[kc] = *(const bf16x8*)(qrow + kc * 16);
    }
    float rl16[16];
#pragma unroll
    for (int r16 = 0; r16 < 16; r16++)
      rl16[r16] = rlw[(size_t)h * S_LEN + qbase + (r16 & 3) + 8 * (r16 >> 2) + 4 * h2];

    float* sc = scores + (size_t)kvh * S_LEN;
    const int ntw = (qbase + 31) / 64 + 1;
    for (int t = 0; t < ntw; t++) {
      const int kb = t * 64;
      f32x16 sg[2];
      sg[0] = (f32x16)(0.f); sg[1] = (f32x16)(0.f);
      __builtin_amdgcn_s_setprio(1);
#pragma unroll
      for (int kc = 0; kc < 8; kc++)
#pragma unroll
        for (int bl = 0; bl < 2; bl++) {
          bf16x8 kf = *(const bf16x8*)(KrB + (size_t)(kb + bl * 32 + l31) * HD + kc * 16 + h2 * 8);
          sg[bl] = __builtin_amdgcn_mfma_f32_32x32x16_bf16(qf[kc], kf, sg[bl], 0, 0, 0);
        }
      __builtin_amdgcn_s_setprio(0);

      const bool diag = (kb + 63 > qbase);
#pragma unroll
      for (int bl = 0; bl < 2; bl++) {
        int key = kb + bl * 32 + l31;
        float sum = 0.f;
#pragma unroll
        for (int r16 = 0; r16 < 16; r16++) {
          float pv = exp2f(sg[bl][r16] * CS) * rl16[r16];
          if (diag && key > qbase + (r16 & 3) + 8 * (r16 >> 2) + 4 * h2) pv = 0.f;
          sum += pv;
        }
        sum += __shfl_xor(sum, 32);
        if (lane < 32) atomicAdd(&sc[key], sum);
      }
    }
  }
}

// ---------------- launch ----------------
extern "C" void kernel_launch(void* const* d_in, const int* in_sizes, int n_in,
                              void* d_out, int out_size, void* d_ws, size_t ws_size,
                              hipStream_t stream) {
  const float* hs = (const float*)d_in[0];
  const float* wq = (const float*)d_in[1];
  const float* wk = (const float*)d_in[2];
  const float* wv = (const float*)d_in[3];
  const float* wo = (const float*)d_in[4];
  const int* pos = (const int*)d_in[5];
  float* out = (float*)d_out;

  char* ws = (char*)d_ws;
  const size_t off_hs   = 0;
  const size_t off_wqT  = off_hs   + (size_t)S_LEN * HID_DIM * 2;
  const size_t off_wkT  = off_wqT  + (size_t)HID_DIM * HID_DIM * 2;
  const size_t off_wvT  = off_wkT  + (size_t)1024 * HID_DIM * 2;
  const size_t off_woT  = off_wvT  + (size_t)1024 * HID_DIM * 2;
  const size_t off_Qr   = off_woT  + (size_t)HID_DIM * HID_DIM * 2;
  const size_t off_Kr   = off_Qr   + (size_t)NH * S_LEN * HD * 2;
  const size_t off_Vt   = off_Kr   + (size_t)NKV * S_LEN * HD * 2;
  const size_t off_attn = off_Vt   + (size_t)NKV * HD * S_LEN * 2;
  const size_t off_rlw  = off_attn + (size_t)S_LEN * HID_DIM * 2;

  short* hsb  = (short*)(ws + off_hs);
  short* wqT  = (short*)(ws + off_wqT);
  short* wkT  = (short*)(ws + off_wkT);
  short* wvT  = (short*)(ws + off_wvT);
  short* woT  = (short*)(ws + off_woT);
  short* Qr   = (short*)(ws + off_Qr);
  short* Kr   = (short*)(ws + off_Kr);
  short* Vt   = (short*)(ws + off_Vt);
  short* attb = (short*)(ws + off_attn);
  float* rlw  = (float*)(ws + off_rlw);

  cvt_kernel<<<dim3((S_LEN * HID_DIM) / 1024), 256, 0, stream>>>(hs, hsb, S_LEN * HID_DIM);
  tconv_kernel<<<dim3(128, 128), 256, 0, stream>>>(wq, wqT, HID_DIM, HID_DIM);
  tconv_kernel<<<dim3(32, 128), 256, 0, stream>>>(wk, wkT, HID_DIM, 1024);
  tconv_kernel<<<dim3(32, 128), 256, 0, stream>>>(wv, wvT, HID_DIM, 1024);
  tconv_kernel<<<dim3(128, 128), 256, 0, stream>>>(wo, woT, HID_DIM, HID_DIM);

  gemm_bt_kernel<3><<<768, 256, 0, stream>>>(hsb, wqT, Qr, S_LEN, 6144, HID_DIM, 8, 12);

  rope_kernel<<<dim3(S_LEN, 10), dim3(64, 4), 0, stream>>>(Qr, Kr, pos);

  hipMemsetAsync(out + (size_t)S_LEN * HID_DIM, 0, (size_t)NKV * S_LEN * sizeof(float), stream);
  attn_kernel<<<1024, 256, 0, stream>>>(Qr, Kr, Vt, attb, rlw);

  oproj_fused_kernel<<<1024, 256, 0, stream>>>(attb, woT, out, Qr, Kr, rlw,
                                               out + (size_t)S_LEN * HID_DIM);
}

// Round 14
// 388.052 us; speedup vs baseline: 1.1931x; 1.0289x over previous
//
#include <hip/hip_runtime.h>
#include <hip/hip_bf16.h>
#include <cstdint>
#include <cstddef>

#define S_LEN 2048
#define HID_DIM 4096
#define NH 32
#define NKV 8
#define HD 128
#define LOG2E 1.4426950408889634f
#define SCALE 0.08838834764831845f

typedef __attribute__((ext_vector_type(8))) short bf16x8;
typedef __attribute__((ext_vector_type(4))) float f32x4;
typedef __attribute__((ext_vector_type(16))) float f32x16;
typedef __attribute__((ext_vector_type(4))) short short4v;
typedef __attribute__((ext_vector_type(4))) unsigned u32x4;

__device__ __forceinline__ short f2bf(float f) {
  union { float f; unsigned u; } v; v.f = f;
  return (short)((v.u + 0x7fffu + ((v.u >> 16) & 1u)) >> 16);
}
__device__ __forceinline__ float bf2f(short s) {
  union { unsigned u; float f; } v; v.u = ((unsigned)(unsigned short)s) << 16;
  return v.f;
}
__device__ __forceinline__ unsigned cvt_pk_bf16(float lo, float hi) {
  unsigned r;
  asm("v_cvt_pk_bf16_f32 %0, %1, %2" : "=v"(r) : "v"(lo), "v"(hi));
  return r;
}
__device__ __forceinline__ void gld_lds16(const void* g, void* l) {
  __builtin_amdgcn_global_load_lds((const __attribute__((address_space(1))) unsigned*)g,
                                   (__attribute__((address_space(3))) unsigned*)l, 16, 0, 0);
}

#define WAITVM4() asm volatile("s_waitcnt vmcnt(4)" ::: "memory")
#define WAITVM0() asm volatile("s_waitcnt vmcnt(0)" ::: "memory")

// ---------------- fused pre-pass: hs fp32->bf16 + 4 weight transpose-converts ----------------
// One launch replaces 5 memory-bound kernels (removes 4 launch gaps + tails).
// Block ranges: [0,16384) wq tconv, [16384,20480) wk, [20480,24576) wv,
// [24576,40960) wo, [40960,49152) hs cvt. All 256-thread blocks.
__global__ __launch_bounds__(256) void prep_kernel(
    const float* __restrict__ hs, const float* __restrict__ wq, const float* __restrict__ wk,
    const float* __restrict__ wv, const float* __restrict__ wo,
    short* __restrict__ hsb, short* __restrict__ wqT, short* __restrict__ wkT,
    short* __restrict__ wvT, short* __restrict__ woT)
{
  __shared__ float tile[32][33];
  const int id = blockIdx.x;
  const int tid = threadIdx.x;

  if (id >= 40960) {                       // hs fp32 -> bf16 (vectorized)
    int i = ((id - 40960) * 256 + tid) * 4;
    float4 f = *(const float4*)(hs + i);
    short4v o = { f2bf(f.x), f2bf(f.y), f2bf(f.z), f2bf(f.w) };
    *(short4v*)(hsb + i) = o;
    return;
  }

  const float* in; short* out; int C, t;
  if (id < 16384)      { in = wq; out = wqT; C = 4096; t = id; }
  else if (id < 20480) { in = wk; out = wkT; C = 1024; t = id - 16384; }
  else if (id < 24576) { in = wv; out = wvT; C = 1024; t = id - 20480; }
  else                 { in = wo; out = woT; C = 4096; t = id - 24576; }
  const int R = 4096;
  const int nbx = C >> 5;
  const int by = t / nbx, bx = t - by * nbx;
  const int tr = by * 32, tc = bx * 32;
  const int tx = tid & 31, ty = tid >> 5;  // ty 0..7
#pragma unroll
  for (int i = 0; i < 32; i += 8)
    tile[ty + i][tx] = in[(size_t)(tr + ty + i) * C + tc + tx];
  __syncthreads();
#pragma unroll
  for (int i = 0; i < 32; i += 8)
    out[(size_t)(tc + ty + i) * R + tr + tx] = f2bf(tile[tx][ty + i]);
}

// ---------------- GEMM: C[M][N] = A[M][K] * Bt[N][K]^T ----------------
// Double-buffered LDS, counted vmcnt, 4 blocks/CU, per-XCD squarish regions.
// MODE 2: write fp32 out[m][n]
// MODE 3: fused QKV epilogue.
template<int MODE>
__global__ __launch_bounds__(256, 4) void gemm_bt_kernel(
    const short* __restrict__ A, const short* __restrict__ Bt,
    void* __restrict__ Cout, int M, int N, int K, int rchunk, int cchunk)
{
  __shared__ short As[2][128 * 32];
  __shared__ short Bs[2][128 * 32];
  const int tid = threadIdx.x;
  const int lane = tid & 63;
  const int w = tid >> 6;
  const int wm = w >> 1, wn = w & 1;
  const int xcd = blockIdx.x & 7;
  const int local = blockIdx.x >> 3;
  const int by = (xcd >> 2) * rchunk + (local % rchunk);
  const int bx = (xcd & 3) * cchunk + (local / rchunk);
  const int m0 = by * 128, n0 = bx * 128;

  auto stage = [&](int bb, int k0) {
#pragma unroll
    for (int rep = 0; rep < 2; rep++) {
      int c = rep * 256 + tid;
      int row = c >> 2, slot = c & 3;
      int gs = slot ^ (row & 3);
      gld_lds16(A + (size_t)(m0 + row) * K + k0 + gs * 8, &As[bb][c * 8]);
      gld_lds16(Bt + (size_t)(n0 + row) * K + k0 + gs * 8, &Bs[bb][c * 8]);
    }
  };

  f32x4 acc[4][4];
#pragma unroll
  for (int i = 0; i < 4; i++)
#pragma unroll
    for (int j = 0; j < 4; j++) acc[i][j] = (f32x4){0.f, 0.f, 0.f, 0.f};

  const int NT = K >> 5;
  stage(0, 0);
  for (int kt = 0; kt < NT; kt++) {
    const int b = kt & 1;
    if (kt + 1 < NT) { stage(b ^ 1, (kt + 1) << 5); WAITVM4(); }
    else             { WAITVM0(); }
    __builtin_amdgcn_s_barrier();

    bf16x8 af[4], bf[4];
#pragma unroll
    for (int ms = 0; ms < 4; ms++) {
      int row = wm * 64 + ms * 16 + (lane & 15);
      af[ms] = *(const bf16x8*)(&As[b][row * 32 + (((lane >> 4) ^ (row & 3)) << 3)]);
    }
#pragma unroll
    for (int ns = 0; ns < 4; ns++) {
      int row = wn * 64 + ns * 16 + (lane & 15);
      bf[ns] = *(const bf16x8*)(&Bs[b][row * 32 + (((lane >> 4) ^ (row & 3)) << 3)]);
    }
#pragma unroll
    for (int ms = 0; ms < 4; ms++)
#pragma unroll
      for (int ns = 0; ns < 4; ns++)
        acc[ms][ns] = __builtin_amdgcn_mfma_f32_16x16x32_bf16(af[ms], bf[ns], acc[ms][ns], 0, 0, 0);

    __builtin_amdgcn_s_barrier();
  }

#pragma unroll
  for (int ms = 0; ms < 4; ms++) {
    int mb = m0 + wm * 64 + ms * 16 + ((lane >> 4) << 2);
#pragma unroll
    for (int ns = 0; ns < 4; ns++) {
      int n = n0 + wn * 64 + ns * 16 + (lane & 15);
      if (MODE == 3) {
        short* o = (short*)Cout;
        if (n < NH * HD) {
          int head = n >> 7, d = n & 127;
#pragma unroll
          for (int r = 0; r < 4; r++)
            o[((size_t)head * M + (mb + r)) * HD + d] = f2bf(acc[ms][ns][r]);
        } else if (n < (NH + NKV) * HD) {
          int head = (n - NH * HD) >> 7, d = n & 127;
          short* ok = o + (size_t)NH * S_LEN * HD;
#pragma unroll
          for (int r = 0; r < 4; r++)
            ok[((size_t)head * M + (mb + r)) * HD + d] = f2bf(acc[ms][ns][r]);
        } else {
          int head = (n - (NH + NKV) * HD) >> 7, d = n & 127;
          short* ov = o + (size_t)(NH + NKV) * S_LEN * HD;
          short4v pk;
#pragma unroll
          for (int r = 0; r < 4; r++) pk[r] = f2bf(acc[ms][ns][r]);
          *(short4v*)(ov + ((size_t)head * HD + d) * M + mb) = pk;
        }
      } else {
        float* o = (float*)Cout;
#pragma unroll
        for (int r = 0; r < 4; r++)
          o[(size_t)(mb + r) * N + n] = acc[ms][ns][r];
      }
    }
  }
}

// ---------------- RoPE in-place on Q [NH][S][HD] and K [NKV][S][HD] (bf16) ----------------
__global__ void rope_kernel(short* __restrict__ q, short* __restrict__ k,
                            const int* __restrict__ pos_ids) {
  const int s = blockIdx.x;
  const int hh = blockIdx.y * 4 + threadIdx.y;  // 0..39
  const int d = threadIdx.x;                    // 0..63
  const float pos = (float)pos_ids[s];
  const float inv = __expf(-(float)d * 0.14391157f); // ln(10000)/64
  float sn, c;
  __sincosf(pos * inv, &sn, &c);
  short* base = (hh < NH) ? (q + ((size_t)hh * S_LEN + s) * HD)
                          : (k + ((size_t)(hh - NH) * S_LEN + s) * HD);
  float x1 = bf2f(base[d]), x2 = bf2f(base[d + 64]);
  base[d] = f2bf(x1 * c - x2 * sn);
  base[d + 64] = f2bf(x2 * c + x1 * sn);
}

// ---------------- flash attention + eviction scores (32x32x16 MFMA) ----------------
// r11 verbatim (proven 145us): 1024 blocks x 256 threads (4 waves = 2 rowgroups
// x 2 key-halves), one 64-row strip per block (heavy-first), kvh == XCD.
// LDS 48.5KB -> 3 blocks/CU: K double-buffered (32KB, key bits 2<->3 swapped
// -> swapped QK^T output lane-local for PV A-frag); V single-buffered (16KB;
// staged after barrier A, drained by vmcnt(4) before barrier B while next K
// stays in flight); colsums atomicAdd directly to L2 scores.
// Fixed softmax basis m==0; l deferred; O/l combined across key-halves via
// LDS (obuf aliases Ks). Phase 2: barrier-free, K fragments direct from L2.
__global__ __launch_bounds__(256, 3) void attn_kernel(
    const short* __restrict__ Qr, const short* __restrict__ Kr, const short* __restrict__ Vt,
    short* __restrict__ attn_out, float* __restrict__ scores)
{
  __shared__ short Ks[2][64 * 128];  // 32KB dbuf; aliased as obuf after ph1
  __shared__ short Vs[128 * 64];     // 16KB single buffer
  __shared__ float lbuf[128];        // [0..63] lsum(kh=0), [64..127] 1/l

  const int tid = threadIdx.x;
  const int lane = tid & 63;
  const int w = tid >> 6;        // 0..3
  const int r = w & 1;           // row group
  const int kh = w >> 1;         // key half
  const int h2 = lane >> 5;
  const int l31 = lane & 31;
  const int xcd = blockIdx.x & 7;
  const int j = blockIdx.x >> 3; // 0..127
  const int h = xcd * 4 + (j & 3);
  const int qt = 31 - (j >> 2);  // heavy strips dispatched first
  const int kvh = xcd;
  const float CS = SCALE * LOG2E;

  const short* KrB = Kr + (size_t)kvh * S_LEN * HD;
  const short* VtB = Vt + (size_t)kvh * HD * S_LEN;

  const int nt = qt + 1;
  const int qbase = qt * 64 + r * 32;
  const int qglob = qbase + l31;

  float* obuf = (float*)Ks;      // 8192 floats = 32KB, valid after ph1

  auto stageK = [&](int bb, int t) {
    const int kb2 = t * 64;
#pragma unroll
    for (int rep = 0; rep < 4; rep++) {
      int c = rep * 256 + tid;
      int x = c >> 4, slot = c & 15;
      int key = (x & 0x33) | ((x & 4) << 1) | ((x & 8) >> 1);  // swap bits 2,3
      int gs = slot ^ (x & 7);
      gld_lds16(KrB + (size_t)(kb2 + key) * HD + gs * 8, &Ks[bb][c * 8]);
    }
  };
  auto stageV = [&](int t) {
    const int kb2 = t * 64;
#pragma unroll
    for (int rep = 0; rep < 4; rep++) {
      int c = rep * 256 + tid;
      int d = c >> 3, slot = c & 7;
      int gs = slot ^ (d & 7);
      gld_lds16(VtB + (size_t)d * S_LEN + kb2 + gs * 8, &Vs[c * 8]);
    }
  };

  // Q fragments: q = qglob, hd = kc*16 + h2*8 + e
  bf16x8 qf[8];
  {
    const short* qrow = Qr + ((size_t)h * S_LEN + qglob) * HD + h2 * 8;
#pragma unroll
    for (int kc = 0; kc < 8; kc++) qf[kc] = *(const bf16x8*)(qrow + kc * 16);
  }

  f32x16 oacc[4];
#pragma unroll
  for (int i = 0; i < 4; i++) oacc[i] = (f32x16)(0.f);
  float lsum = 0.f;

  // ---------- phase 1 ----------
  stageK(0, 0);
  for (int t = 0; t < nt; t++) {
    const int b = t & 1;
    const int kb = t * 64;
    WAITVM0();                       // K(t) landed
    __builtin_amdgcn_s_barrier();    // barrier A: Ks[b] ready, Vs free

    stageV(t);
    if (t + 1 < nt) stageK(b ^ 1, t + 1);

    // QK^T swapped: C[permkey][q], this wave's key half kh
    f32x16 sf = (f32x16)(0.f);
    const int x = kh * 32 + l31;
    __builtin_amdgcn_s_setprio(1);
#pragma unroll
    for (int kc = 0; kc < 8; kc++) {
      bf16x8 kf = *(const bf16x8*)(&Ks[b][x * 128 + (((kc * 2 + h2) ^ (x & 7)) << 3)]);
      sf = __builtin_amdgcn_mfma_f32_32x32x16_bf16(kf, qf[kc], sf, 0, 0, 0);
    }
    __builtin_amdgcn_s_setprio(0);

    // softmax (fixed basis 0); key of sf[4a+cc] = kb + kh*32 + (a>>1)*16 + h2*8 + (a&1)*4 + cc
    float pv16[16];
    const bool diag = (kb + 63 > qbase);
#pragma unroll
    for (int a = 0; a < 4; a++)
#pragma unroll
      for (int cc = 0; cc < 4; cc++) {
        float pv = exp2f(sf[a * 4 + cc] * CS);
        if (diag) {
          int key = kb + kh * 32 + (a >> 1) * 16 + h2 * 8 + (a & 1) * 4 + cc;
          if (key > qglob) pv = 0.f;
        }
        pv16[a * 4 + cc] = pv;
        lsum += pv;
      }

    bf16x8 pa[2];
#pragma unroll
    for (int s = 0; s < 2; s++) {
      u32x4 pw;
      pw[0] = cvt_pk_bf16(pv16[8 * s + 0], pv16[8 * s + 1]);
      pw[1] = cvt_pk_bf16(pv16[8 * s + 2], pv16[8 * s + 3]);
      pw[2] = cvt_pk_bf16(pv16[8 * s + 4], pv16[8 * s + 5]);
      pw[3] = cvt_pk_bf16(pv16[8 * s + 6], pv16[8 * s + 7]);
      pa[s] = __builtin_bit_cast(bf16x8, pw);
    }

    if (t + 1 < nt) WAITVM4();       // drain V(t), keep K(t+1) in flight
    else           WAITVM0();
    __builtin_amdgcn_s_barrier();    // barrier B: Vs valid

    // PV: C[q][d], partial over this key half
    __builtin_amdgcn_s_setprio(1);
#pragma unroll
    for (int s = 0; s < 2; s++) {
      const int g = kh * 2 + s;      // 16-wide key slice
#pragma unroll
      for (int db = 0; db < 4; db++) {
        int d = db * 32 + l31;
        bf16x8 vf = *(const bf16x8*)(&Vs[d * 64 + (((g * 2 + h2) ^ (d & 7)) << 3)]);
        oacc[db] = __builtin_amdgcn_mfma_f32_32x32x16_bf16(pa[s], vf, oacc[db], 0, 0, 0);
      }
    }
    __builtin_amdgcn_s_setprio(0);
  }

  __builtin_amdgcn_s_barrier();      // all PV reads done; Ks reusable as obuf

  // ---------- O / l combine across key-halves ----------
  lsum += __shfl_xor(lsum, 32);      // combine h2 halves
  if (kh == 0) {
#pragma unroll
    for (int db = 0; db < 4; db++)
#pragma unroll
      for (int r16 = 0; r16 < 16; r16++) {
        int crow = (r16 & 3) + 8 * (r16 >> 2) + 4 * h2;
        obuf[(r * 32 + crow) * 128 + db * 32 + l31] = oacc[db][r16];
      }
    if (lane < 32) lbuf[r * 32 + l31] = lsum;
  }
  __builtin_amdgcn_s_barrier();

  if (kh == 1) {
    float ltot = lsum + lbuf[r * 32 + l31];
    float rlv = 1.f / ltot;
    float rl16[16];
#pragma unroll
    for (int r16 = 0; r16 < 16; r16++)
      rl16[r16] = __shfl(rlv, (r16 & 3) + 8 * (r16 >> 2) + 4 * h2);
#pragma unroll
    for (int db = 0; db < 4; db++) {
      int d = db * 32 + l31;
#pragma unroll
      for (int r16 = 0; r16 < 16; r16++) {
        int crow = (r16 & 3) + 8 * (r16 >> 2) + 4 * h2;
        float o = oacc[db][r16] + obuf[(r * 32 + crow) * 128 + d];
        attn_out[(size_t)(qbase + crow) * HID_DIM + h * HD + d] = f2bf(o * rl16[r16]);
      }
    }
    if (lane < 32) lbuf[64 + r * 32 + l31] = rlv;
  }
  __builtin_amdgcn_s_barrier();

  // per-row reciprocals for phase 2
  float rlv = lbuf[64 + r * 32 + l31];
  float rl16[16];
#pragma unroll
  for (int r16 = 0; r16 < 16; r16++)
    rl16[r16] = __shfl(rlv, (r16 & 3) + 8 * (r16 >> 2) + 4 * h2);

  // ---------- phase 2: colsums, direct from L2, barrier-free ----------
  float* sc = scores + (size_t)kvh * S_LEN;
  for (int t = kh; t < nt; t += 2) {
    const int kb = t * 64;
    f32x16 sg[2];
    sg[0] = (f32x16)(0.f); sg[1] = (f32x16)(0.f);
    __builtin_amdgcn_s_setprio(1);
#pragma unroll
    for (int kc = 0; kc < 8; kc++)
#pragma unroll
      for (int bl = 0; bl < 2; bl++) {
        bf16x8 kf = *(const bf16x8*)(KrB + (size_t)(kb + bl * 32 + l31) * HD + kc * 16 + h2 * 8);
        sg[bl] = __builtin_amdgcn_mfma_f32_32x32x16_bf16(qf[kc], kf, sg[bl], 0, 0, 0);
      }
    __builtin_amdgcn_s_setprio(0);

    const bool diag = (kb + 63 > qbase);
#pragma unroll
    for (int bl = 0; bl < 2; bl++) {
      int key = kb + bl * 32 + l31;
      float sum = 0.f;
#pragma unroll
      for (int r16 = 0; r16 < 16; r16++) {
        float pv = exp2f(sg[bl][r16] * CS) * rl16[r16];
        if (diag && key > qbase + (r16 & 3) + 8 * (r16 >> 2) + 4 * h2) pv = 0.f;
        sum += pv;
      }
      sum += __shfl_xor(sum, 32);
      if (lane < 32) atomicAdd(&sc[key], sum);
    }
  }
}

// ---------------- launch ----------------
extern "C" void kernel_launch(void* const* d_in, const int* in_sizes, int n_in,
                              void* d_out, int out_size, void* d_ws, size_t ws_size,
                              hipStream_t stream) {
  const float* hs = (const float*)d_in[0];
  const float* wq = (const float*)d_in[1];
  const float* wk = (const float*)d_in[2];
  const float* wv = (const float*)d_in[3];
  const float* wo = (const float*)d_in[4];
  const int* pos = (const int*)d_in[5];
  float* out = (float*)d_out;

  char* ws = (char*)d_ws;
  const size_t off_hs   = 0;
  const size_t off_wqT  = off_hs   + (size_t)S_LEN * HID_DIM * 2;
  const size_t off_wkT  = off_wqT  + (size_t)HID_DIM * HID_DIM * 2;
  const size_t off_wvT  = off_wkT  + (size_t)1024 * HID_DIM * 2;
  const size_t off_woT  = off_wvT  + (size_t)1024 * HID_DIM * 2;
  const size_t off_Qr   = off_woT  + (size_t)HID_DIM * HID_DIM * 2;
  const size_t off_Kr   = off_Qr   + (size_t)NH * S_LEN * HD * 2;
  const size_t off_Vt   = off_Kr   + (size_t)NKV * S_LEN * HD * 2;
  const size_t off_attn = off_Vt   + (size_t)NKV * HD * S_LEN * 2;

  short* hsb  = (short*)(ws + off_hs);
  short* wqT  = (short*)(ws + off_wqT);
  short* wkT  = (short*)(ws + off_wkT);
  short* wvT  = (short*)(ws + off_wvT);
  short* woT  = (short*)(ws + off_woT);
  short* Qr   = (short*)(ws + off_Qr);
  short* Kr   = (short*)(ws + off_Kr);
  short* Vt   = (short*)(ws + off_Vt);
  short* attb = (short*)(ws + off_attn);

  // fused pre-pass: 16384 (wq) + 4096 (wk) + 4096 (wv) + 16384 (wo) + 8192 (hs cvt)
  prep_kernel<<<49152, 256, 0, stream>>>(hs, wq, wk, wv, wo, hsb, wqT, wkT, wvT, woT);

  gemm_bt_kernel<3><<<768, 256, 0, stream>>>(hsb, wqT, Qr, S_LEN, 6144, HID_DIM, 8, 12);

  rope_kernel<<<dim3(S_LEN, 10), dim3(64, 4), 0, stream>>>(Qr, Kr, pos);

  hipMemsetAsync(out + (size_t)S_LEN * HID_DIM, 0, (size_t)NKV * S_LEN * sizeof(float), stream);
  attn_kernel<<<1024, 256, 0, stream>>>(Qr, Kr, Vt, attb, out + (size_t)S_LEN * HID_DIM);

  gemm_bt_kernel<2><<<512, 256, 0, stream>>>(attb, woT, out, S_LEN, HID_DIM, HID_DIM, 8, 8);
}